// Round 10
// baseline (113.779 us; speedup 1.0000x reference)
//
#include <hip/hip_runtime.h>
#include <math.h>

static constexpr int TPB   = 256;
static constexpr int MPB   = 2048;        // members per seg block
static constexpr int WMEM  = 512;         // members per wave
static constexpr int PMEM  = 256;         // members per phase (2 phases/wave)
static constexpr int LOCAL_BINS = 448;    // span/block ~43 typical; global fallback covers overflow
static constexpr int STAGE_F4   = 192;    // UNPADDED: natural layout is bank-balanced
static constexpr int ROWS_PER_BLOCK = 32; // mlp: 4 waves x 8 rows

// ---------------------------------------------------------------------------
// Workspace zero (rocclr fillBufferAligned is slow for small fills).
// ---------------------------------------------------------------------------
__global__ __launch_bounds__(256)
void zero_ws_kernel(float4* __restrict__ ws, int n4) {
  int i = blockIdx.x * blockDim.x + threadIdx.x;
  int stride = gridDim.x * blockDim.x;
  for (; i < n4; i += stride) ws[i] = make_float4(0.f, 0.f, 0.f, 0.f);
}

// ---------------------------------------------------------------------------
// Fused kernel, Bresenham role interleave (R8 geometry).
//
// seg role: 2048 members/block, LDS bins, 2 block barriers. All global loads
//   coalesced (16B/lane stride-16): pos bulk-copied into per-wave LDS stage.
//   R10: stage is UNPADDED — reads are 3x ds_read_b128 at 48B lane stride,
//   whose start banks (12*lane mod 32) partition all 32 banks per 8 lanes
//   (minimal 2-way aliasing = free, m136); writes are stride-16B sequential
//   (same). R9's pad misaligned both patterns -> 900K bank conflicts.
// mlp role: unchanged from R8 (2 quads/wave, 8 outstanding loads/lane).
// ---------------------------------------------------------------------------
__global__ __launch_bounds__(TPB)
void fused_kernel(const float* __restrict__ lm,
                  const float* __restrict__ pos,
                  const int*   __restrict__ idx,
                  const float* __restrict__ gf,
                  const float* __restrict__ w,
                  const float* __restrict__ bptr,
                  const float* __restrict__ noise,
                  const int*   __restrict__ temp_ptr,
                  float* __restrict__ seg_sum,     // [G]
                  float* __restrict__ center_raw,  // [3G]
                  float* __restrict__ out,         // [5G]
                  int M, int G, int nseg, int ntot) {
  __shared__ float  bins[LOCAL_BINS * 4];
  __shared__ float4 stage[4][STAGE_F4];

  long long r = blockIdx.x;
  int segcum  = (int)((r * (long long)nseg) / ntot);
  int segcum1 = (int)(((r + 1) * (long long)nseg) / ntot);

  if (segcum1 != segcum) {
    // ---------------- seg role ----------------
    int blockBase = segcum * MPB;
    if (blockBase >= M) return;
    int blockEnd = min(blockBase + MPB, M);
    int g_first = idx[blockBase];
    int g_last  = idx[blockEnd - 1];
    int span    = g_last - g_first + 1;
    int nbins   = min(span, LOCAL_BINS);

    for (int i = threadIdx.x; i < nbins * 4; i += TPB) bins[i] = 0.f;
    __syncthreads();

    int wid  = threadIdx.x >> 6;
    int lane = threadIdx.x & 63;

    auto flush = [&](int g, float se, float sx, float sy, float sz) {
      int off = g - g_first;
      if (off < LOCAL_BINS) {
        unsafeAtomicAdd(&bins[off*4+0], se);
        unsafeAtomicAdd(&bins[off*4+1], sx);
        unsafeAtomicAdd(&bins[off*4+2], sy);
        unsafeAtomicAdd(&bins[off*4+3], sz);
      } else {               // span-overflow fallback (statistically ~never)
        unsafeAtomicAdd(&seg_sum[g], se);
        unsafeAtomicAdd(&center_raw[3*g+0], sx);
        unsafeAtomicAdd(&center_raw[3*g+1], sy);
        unsafeAtomicAdd(&center_raw[3*g+2], sz);
      }
    };

    #pragma unroll
    for (int h = 0; h < 2; h++) {
      int memBase = blockBase + wid * WMEM + h * PMEM;
      if (memBase < M) {
        if (memBase + PMEM <= M) {
          // -------- full phase: all loads coalesced --------
          const float4* p4 = (const float4*)(pos + (size_t)memBase * 3);
          #pragma unroll
          for (int k = 0; k < 3; k++) {
            stage[wid][lane + 64 * k] = p4[lane + 64 * k];
          }
          const int4*   i4 = (const int4*)(idx + memBase);
          const float4* l4 = (const float4*)(lm + memBase);
          int4   ib = i4[lane];
          float4 lv = l4[lane];
          asm volatile("s_waitcnt lgkmcnt(0)" ::: "memory");
          int j0 = 3 * lane;
          float4 s0 = stage[wid][j0    ];
          float4 s1 = stage[wid][j0 + 1];
          float4 s2 = stage[wid][j0 + 2];

          float eb[4];
          eb[0] = __expf(lv.x); eb[1] = __expf(lv.y);
          eb[2] = __expf(lv.z); eb[3] = __expf(lv.w);
          int   ibv[4] = {ib.x, ib.y, ib.z, ib.w};
          float px[4] = {s0.x, s0.w, s1.z, s2.y};
          float py[4] = {s0.y, s1.x, s1.w, s2.z};
          float pz[4] = {s0.z, s1.y, s2.x, s2.w};

          if (ib.x == ib.w) {
            // fast path (~92%): all 4 members in one segment
            float se = eb[0]+eb[1]+eb[2]+eb[3];
            float sx = px[0]*eb[0]+px[1]*eb[1]+px[2]*eb[2]+px[3]*eb[3];
            float sy = py[0]*eb[0]+py[1]*eb[1]+py[2]*eb[2]+py[3]*eb[3];
            float sz = pz[0]*eb[0]+pz[1]*eb[1]+pz[2]*eb[2]+pz[3]*eb[3];
            flush(ib.x, se, sx, sy, sz);
          } else {
            int cur = ibv[0];
            float se = 0.f, sx = 0.f, sy = 0.f, sz = 0.f;
            #pragma unroll
            for (int j = 0; j < 4; j++) {
              if (ibv[j] != cur) {
                flush(cur, se, sx, sy, sz);
                cur = ibv[j]; se = 0.f; sx = 0.f; sy = 0.f; sz = 0.f;
              }
              se += eb[j];
              sx += px[j] * eb[j];
              sy += py[j] * eb[j];
              sz += pz[j] * eb[j];
            }
            flush(cur, se, sx, sy, sz);
          }
        } else {
          // -------- ragged tail phase (last block only): scalar loads --------
          int mstart = memBase + 4 * lane;
          if (mstart < M) {
            int nj = min(4, M - mstart);
            int cur = idx[mstart];
            float se = 0.f, sx = 0.f, sy = 0.f, sz = 0.f;
            for (int j = 0; j < nj; j++) {
              int m = mstart + j;
              int g = idx[m];
              float e = __expf(lm[m]);
              if (g != cur) {
                flush(cur, se, sx, sy, sz);
                cur = g; se = 0.f; sx = 0.f; sy = 0.f; sz = 0.f;
              }
              se += e;
              sx += pos[(size_t)m*3+0] * e;
              sy += pos[(size_t)m*3+1] * e;
              sz += pos[(size_t)m*3+2] * e;
            }
            flush(cur, se, sx, sy, sz);
          }
        }
      }
      // wave-local phase boundary: same-wave LDS ops execute in order;
      // fence keeps the compiler from reordering across phases.
      asm volatile("" ::: "memory");
    }
    __syncthreads();

    for (int i = threadIdx.x; i < nbins; i += TPB) {
      int g = g_first + i;
      float s0 = bins[i*4+0], s1 = bins[i*4+1], s2 = bins[i*4+2], s3 = bins[i*4+3];
      if (g == g_first || g == g_last) {
        unsafeAtomicAdd(&seg_sum[g], s0);
        unsafeAtomicAdd(&center_raw[3*g+0], s1);
        unsafeAtomicAdd(&center_raw[3*g+1], s2);
        unsafeAtomicAdd(&center_raw[3*g+2], s3);
      } else {
        seg_sum[g] = s0;
        center_raw[3*g+0] = s1;
        center_raw[3*g+1] = s2;
        center_raw[3*g+2] = s3;
      }
    }
  } else {
    // ---------------- mlp role: 2 quads per wave (R8) ----------------
    int mb   = (int)(r - segcum);
    int wid  = threadIdx.x >> 6;
    int lane = threadIdx.x & 63;
    int sub  = lane & 15;
    int rg   = lane >> 4;

    int row0 = (mb * 4 + wid) * 8;
    int rowA = row0 + rg;
    int rowB = row0 + 4 + rg;

    const float4* w4 = (const float4*)w;
    float4 wv0 = w4[sub +  0], wv1 = w4[sub + 16],
           wv2 = w4[sub + 32], wv3 = w4[sub + 48];

    float dA = 0.f, dB = 0.f;
    if (rowA < G) {
      const float4* ga = (const float4*)(gf + (size_t)rowA * 256);
      const float4* gb = (const float4*)(gf + (size_t)rowB * 256);
      float4 a0 = ga[sub +  0], a1 = ga[sub + 16],
             a2 = ga[sub + 32], a3 = ga[sub + 48];
      float4 b0 = gb[sub +  0], b1 = gb[sub + 16],
             b2 = gb[sub + 32], b3 = gb[sub + 48];
      dA  = a0.x*wv0.x + a0.y*wv0.y + a0.z*wv0.z + a0.w*wv0.w;
      dA += a1.x*wv1.x + a1.y*wv1.y + a1.z*wv1.z + a1.w*wv1.w;
      dA += a2.x*wv2.x + a2.y*wv2.y + a2.z*wv2.z + a2.w*wv2.w;
      dA += a3.x*wv3.x + a3.y*wv3.y + a3.z*wv3.z + a3.w*wv3.w;
      dB  = b0.x*wv0.x + b0.y*wv0.y + b0.z*wv0.z + b0.w*wv0.w;
      dB += b1.x*wv1.x + b1.y*wv1.y + b1.z*wv1.z + b1.w*wv1.w;
      dB += b2.x*wv2.x + b2.y*wv2.y + b2.z*wv2.z + b2.w*wv2.w;
      dB += b3.x*wv3.x + b3.y*wv3.y + b3.z*wv3.z + b3.w*wv3.w;
    }
    #pragma unroll
    for (int m = 8; m >= 1; m >>= 1) {
      dA += __shfl_xor(dA, m, 64);
      dB += __shfl_xor(dB, m, 64);
    }

    if (sub == 0 && rowA < G) {
      float bb = bptr[0];
      int iv = temp_ptr[0];
      float tT = (iv > -(1 << 23) && iv < (1 << 23)) ? (float)iv : __int_as_float(iv);

      float logitA = 8.8f * tanhf(dA + bb);
      float nA = noise[rowA];
      float xA = (logitA + (logf(nA) - log1pf(-nA))) / tT;
      out[rowA]     = fminf(xA, 0.f) - log1pf(expf(-fabsf(xA)));
      out[G + rowA] = logitA;

      if (rowB < G) {
        float logitB = 8.8f * tanhf(dB + bb);
        float nB = noise[rowB];
        float xB = (logitB + (logf(nB) - log1pf(-nB))) / tT;
        out[rowB]     = fminf(xB, 0.f) - log1pf(expf(-fabsf(xB)));
        out[G + rowB] = logitB;
      }
    }
  }
}

// ---------------------------------------------------------------------------
// Center normalize: out[2G + i] = center_raw[i] / seg_sum[i/3] (0 if empty).
// ---------------------------------------------------------------------------
__global__ __launch_bounds__(256)
void norm_kernel(const float* __restrict__ seg_sum,
                 const float* __restrict__ center_raw,
                 float* __restrict__ out, int G) {
  int i = blockIdx.x * blockDim.x + threadIdx.x;
  int n = 3 * G;
  if (i < n) {
    int g = i / 3;
    float s = seg_sum[g];
    float inv = (s > 0.f) ? (1.f / s) : 0.f;
    out[(size_t)2 * G + i] = center_raw[i] * inv;
  }
}

extern "C" void kernel_launch(void* const* d_in, const int* in_sizes, int n_in,
                              void* d_out, int out_size, void* d_ws, size_t ws_size,
                              hipStream_t stream) {
  const float* gf    = (const float*)d_in[0];
  const float* pos   = (const float*)d_in[1];
  const float* lm    = (const float*)d_in[2];
  const int*   idx   = (const int*)  d_in[3];
  const float* w     = (const float*)d_in[4];
  const float* b     = (const float*)d_in[5];
  const float* noise = (const float*)d_in[6];
  const int*   temp  = (const int*)  d_in[7];
  float* out = (float*)d_out;

  int G = in_sizes[6];
  int M = in_sizes[3];

  float* seg_sum    = (float*)d_ws;
  float* center_raw = seg_sum + G;

  int n4 = (4 * G) / 4;
  hipLaunchKernelGGL(zero_ws_kernel, dim3(784), dim3(256), 0, stream,
                     (float4*)d_ws, n4);

  int nseg = (M + MPB - 1) / MPB;                          // 4688
  int nmlp = (G + ROWS_PER_BLOCK - 1) / ROWS_PER_BLOCK;    // 6250
  int ntot = nseg + nmlp;
  hipLaunchKernelGGL(fused_kernel, dim3(ntot), dim3(TPB), 0, stream,
                     lm, pos, idx, gf, w, b, noise, temp,
                     seg_sum, center_raw, out, M, G, nseg, ntot);

  int nblk = (3 * G + 255) / 256;
  hipLaunchKernelGGL(norm_kernel, dim3(nblk), dim3(256), 0, stream,
                     seg_sum, center_raw, out, G);
}

// Round 11
// 101.562 us; speedup vs baseline: 1.1203x; 1.1203x over previous
//
#include <hip/hip_runtime.h>
#include <math.h>

static constexpr int CHUNK = 8;           // members per thread (seg path)
static constexpr int TPB   = 256;         // threads per block
static constexpr int MPB   = TPB * CHUNK; // 2048 members per seg block
static constexpr int LOCAL_BINS = 640;    // LDS bins cap (span/block ~43 typical)
static constexpr int ROWS_PER_BLOCK = 48; // mlp: 4 waves x 12 rows (3 quads/wave)

// ---------------------------------------------------------------------------
// Workspace zero (rocclr fillBufferAligned is slow for small fills).
// ---------------------------------------------------------------------------
__global__ __launch_bounds__(256)
void zero_ws_kernel(float4* __restrict__ ws, int n4) {
  int i = blockIdx.x * blockDim.x + threadIdx.x;
  int stride = gridDim.x * blockDim.x;
  for (; i < n4; i += stride) ws[i] = make_float4(0.f, 0.f, 0.f, 0.f);
}

// ---------------------------------------------------------------------------
// Fused kernel: R8 structure (best measured: 96.1us). seg role unchanged;
// mlp role deepened 2 quads -> 3 quads per wave (12 outstanding float4
// loads/lane). launch_bounds(256,8) caps VGPR at 64 to keep 8 blocks/CU.
// ---------------------------------------------------------------------------
__global__ __launch_bounds__(TPB, 8)
void fused_kernel(const float* __restrict__ lm,
                  const float* __restrict__ pos,
                  const int*   __restrict__ idx,
                  const float* __restrict__ gf,
                  const float* __restrict__ w,
                  const float* __restrict__ bptr,
                  const float* __restrict__ noise,
                  const int*   __restrict__ temp_ptr,
                  float* __restrict__ seg_sum,     // [G]
                  float* __restrict__ center_raw,  // [3G]
                  float* __restrict__ out,         // [5G]
                  int M, int G, int nseg, int ntot) {
  __shared__ float bins[LOCAL_BINS * 4];

  long long r = blockIdx.x;
  int segcum  = (int)((r * (long long)nseg) / ntot);
  int segcum1 = (int)(((r + 1) * (long long)nseg) / ntot);

  if (segcum1 != segcum) {
    // ---------------- seg role (exact R8) ----------------
    int blockBase = segcum * MPB;
    if (blockBase >= M) return;
    int blockEnd = min(blockBase + MPB, M);
    int g_first = idx[blockBase];
    int g_last  = idx[blockEnd - 1];
    int span    = g_last - g_first + 1;
    int nbins   = min(span, LOCAL_BINS);

    for (int i = threadIdx.x; i < nbins * 4; i += TPB) bins[i] = 0.f;
    __syncthreads();

    int base = blockBase + threadIdx.x * CHUNK;
    if (base < M) {
      auto flush = [&](int g, float se, float sx, float sy, float sz) {
        int off = g - g_first;
        if (off < LOCAL_BINS) {
          unsafeAtomicAdd(&bins[off*4+0], se);
          unsafeAtomicAdd(&bins[off*4+1], sx);
          unsafeAtomicAdd(&bins[off*4+2], sy);
          unsafeAtomicAdd(&bins[off*4+3], sz);
        } else {             // span-overflow fallback (statistically ~never)
          unsafeAtomicAdd(&seg_sum[g], se);
          unsafeAtomicAdd(&center_raw[3*g+0], sx);
          unsafeAtomicAdd(&center_raw[3*g+1], sy);
          unsafeAtomicAdd(&center_raw[3*g+2], sz);
        }
      };

      if (base + CHUNK <= M) {
        const int4*   i4 = (const int4*)(idx + base);
        const float4* l4 = (const float4*)(lm + base);
        const float4* p4 = (const float4*)(pos + (size_t)base * 3);
        int4 ia = i4[0], ic = i4[1];
        float4 la = l4[0], lc = l4[1];
        float4 pA = p4[0], pB = p4[1], pC = p4[2],
               pD = p4[3], pE = p4[4], pF = p4[5];
        int   ib[CHUNK] = {ia.x,ia.y,ia.z,ia.w, ic.x,ic.y,ic.z,ic.w};
        float eb[CHUNK];
        eb[0]=__expf(la.x); eb[1]=__expf(la.y); eb[2]=__expf(la.z); eb[3]=__expf(la.w);
        eb[4]=__expf(lc.x); eb[5]=__expf(lc.y); eb[6]=__expf(lc.z); eb[7]=__expf(lc.w);
        float pb[CHUNK*3] = {pA.x,pA.y,pA.z,pA.w, pB.x,pB.y,pB.z,pB.w,
                             pC.x,pC.y,pC.z,pC.w, pD.x,pD.y,pD.z,pD.w,
                             pE.x,pE.y,pE.z,pE.w, pF.x,pF.y,pF.z,pF.w};

        if (ib[0] == ib[CHUNK-1]) {
          // fast path (~85%): whole chunk in one segment
          float se = 0.f, sx = 0.f, sy = 0.f, sz = 0.f;
          #pragma unroll
          for (int j = 0; j < CHUNK; j++) {
            se += eb[j];
            sx += pb[3*j+0] * eb[j];
            sy += pb[3*j+1] * eb[j];
            sz += pb[3*j+2] * eb[j];
          }
          flush(ib[0], se, sx, sy, sz);
        } else {
          int cur = ib[0];
          float se = 0.f, sx = 0.f, sy = 0.f, sz = 0.f;
          #pragma unroll
          for (int j = 0; j < CHUNK; j++) {
            if (ib[j] != cur) {
              flush(cur, se, sx, sy, sz);
              cur = ib[j]; se = 0.f; sx = 0.f; sy = 0.f; sz = 0.f;
            }
            se += eb[j];
            sx += pb[3*j+0] * eb[j];
            sy += pb[3*j+1] * eb[j];
            sz += pb[3*j+2] * eb[j];
          }
          flush(cur, se, sx, sy, sz);
        }
      } else {
        // ragged tail chunk (last block only)
        int nj = M - base;
        int cur = idx[base];
        float se = 0.f, sx = 0.f, sy = 0.f, sz = 0.f;
        for (int j = 0; j < nj; j++) {
          int m = base + j;
          int g = idx[m];
          float e = __expf(lm[m]);
          if (g != cur) {
            flush(cur, se, sx, sy, sz);
            cur = g; se = 0.f; sx = 0.f; sy = 0.f; sz = 0.f;
          }
          se += e;
          sx += pos[(size_t)m*3+0] * e;
          sy += pos[(size_t)m*3+1] * e;
          sz += pos[(size_t)m*3+2] * e;
        }
        flush(cur, se, sx, sy, sz);
      }
    }
    __syncthreads();

    for (int i = threadIdx.x; i < nbins; i += TPB) {
      int g = g_first + i;
      float s0 = bins[i*4+0], s1 = bins[i*4+1], s2 = bins[i*4+2], s3 = bins[i*4+3];
      if (g == g_first || g == g_last) {
        unsafeAtomicAdd(&seg_sum[g], s0);
        unsafeAtomicAdd(&center_raw[3*g+0], s1);
        unsafeAtomicAdd(&center_raw[3*g+1], s2);
        unsafeAtomicAdd(&center_raw[3*g+2], s3);
      } else {
        seg_sum[g] = s0;
        center_raw[3*g+0] = s1;
        center_raw[3*g+1] = s2;
        center_raw[3*g+2] = s3;
      }
    }
  } else {
    // ---------------- mlp role: 3 quads per wave ----------------
    int mb   = (int)(r - segcum);
    int wid  = threadIdx.x >> 6;
    int lane = threadIdx.x & 63;
    int sub  = lane & 15;
    int rg   = lane >> 4;

    int row0 = (mb * 4 + wid) * 12;
    int rowA = row0 + rg;
    int rowB = row0 + 4 + rg;
    int rowC = row0 + 8 + rg;
    // clamp for address safety (only final block has invalid rows);
    // output writes are guarded by the true row index.
    int ra = min(rowA, G - 1);
    int rb = min(rowB, G - 1);
    int rc = min(rowC, G - 1);

    const float4* w4 = (const float4*)w;
    float4 wv0 = w4[sub +  0], wv1 = w4[sub + 16],
           wv2 = w4[sub + 32], wv3 = w4[sub + 48];

    const float4* ga = (const float4*)(gf + (size_t)ra * 256);
    const float4* gb = (const float4*)(gf + (size_t)rb * 256);
    const float4* gc = (const float4*)(gf + (size_t)rc * 256);
    // issue all 12 loads before any use: 12 outstanding VMEM per lane
    float4 a0 = ga[sub +  0], a1 = ga[sub + 16],
           a2 = ga[sub + 32], a3 = ga[sub + 48];
    float4 b0 = gb[sub +  0], b1 = gb[sub + 16],
           b2 = gb[sub + 32], b3 = gb[sub + 48];
    float4 c0 = gc[sub +  0], c1 = gc[sub + 16],
           c2 = gc[sub + 32], c3 = gc[sub + 48];

    float dA, dB, dC;
    dA  = a0.x*wv0.x + a0.y*wv0.y + a0.z*wv0.z + a0.w*wv0.w;
    dA += a1.x*wv1.x + a1.y*wv1.y + a1.z*wv1.z + a1.w*wv1.w;
    dA += a2.x*wv2.x + a2.y*wv2.y + a2.z*wv2.z + a2.w*wv2.w;
    dA += a3.x*wv3.x + a3.y*wv3.y + a3.z*wv3.z + a3.w*wv3.w;
    dB  = b0.x*wv0.x + b0.y*wv0.y + b0.z*wv0.z + b0.w*wv0.w;
    dB += b1.x*wv1.x + b1.y*wv1.y + b1.z*wv1.z + b1.w*wv1.w;
    dB += b2.x*wv2.x + b2.y*wv2.y + b2.z*wv2.z + b2.w*wv2.w;
    dB += b3.x*wv3.x + b3.y*wv3.y + b3.z*wv3.z + b3.w*wv3.w;
    dC  = c0.x*wv0.x + c0.y*wv0.y + c0.z*wv0.z + c0.w*wv0.w;
    dC += c1.x*wv1.x + c1.y*wv1.y + c1.z*wv1.z + c1.w*wv1.w;
    dC += c2.x*wv2.x + c2.y*wv2.y + c2.z*wv2.z + c2.w*wv2.w;
    dC += c3.x*wv3.x + c3.y*wv3.y + c3.z*wv3.z + c3.w*wv3.w;

    #pragma unroll
    for (int m = 8; m >= 1; m >>= 1) {
      dA += __shfl_xor(dA, m, 64);
      dB += __shfl_xor(dB, m, 64);
      dC += __shfl_xor(dC, m, 64);
    }

    if (sub == 0) {
      float bb = bptr[0];
      int iv = temp_ptr[0];
      float tT = (iv > -(1 << 23) && iv < (1 << 23)) ? (float)iv : __int_as_float(iv);

      if (rowA < G) {
        float logit = 8.8f * tanhf(dA + bb);
        float n = noise[rowA];
        float x = (logit + (logf(n) - log1pf(-n))) / tT;
        out[rowA]     = fminf(x, 0.f) - log1pf(expf(-fabsf(x)));
        out[G + rowA] = logit;
      }
      if (rowB < G) {
        float logit = 8.8f * tanhf(dB + bb);
        float n = noise[rowB];
        float x = (logit + (logf(n) - log1pf(-n))) / tT;
        out[rowB]     = fminf(x, 0.f) - log1pf(expf(-fabsf(x)));
        out[G + rowB] = logit;
      }
      if (rowC < G) {
        float logit = 8.8f * tanhf(dC + bb);
        float n = noise[rowC];
        float x = (logit + (logf(n) - log1pf(-n))) / tT;
        out[rowC]     = fminf(x, 0.f) - log1pf(expf(-fabsf(x)));
        out[G + rowC] = logit;
      }
    }
  }
}

// ---------------------------------------------------------------------------
// Center normalize: out[2G + i] = center_raw[i] / seg_sum[i/3] (0 if empty).
// ---------------------------------------------------------------------------
__global__ __launch_bounds__(256)
void norm_kernel(const float* __restrict__ seg_sum,
                 const float* __restrict__ center_raw,
                 float* __restrict__ out, int G) {
  int i = blockIdx.x * blockDim.x + threadIdx.x;
  int n = 3 * G;
  if (i < n) {
    int g = i / 3;
    float s = seg_sum[g];
    float inv = (s > 0.f) ? (1.f / s) : 0.f;
    out[(size_t)2 * G + i] = center_raw[i] * inv;
  }
}

extern "C" void kernel_launch(void* const* d_in, const int* in_sizes, int n_in,
                              void* d_out, int out_size, void* d_ws, size_t ws_size,
                              hipStream_t stream) {
  const float* gf    = (const float*)d_in[0];
  const float* pos   = (const float*)d_in[1];
  const float* lm    = (const float*)d_in[2];
  const int*   idx   = (const int*)  d_in[3];
  const float* w     = (const float*)d_in[4];
  const float* b     = (const float*)d_in[5];
  const float* noise = (const float*)d_in[6];
  const int*   temp  = (const int*)  d_in[7];
  float* out = (float*)d_out;

  int G = in_sizes[6];
  int M = in_sizes[3];

  float* seg_sum    = (float*)d_ws;
  float* center_raw = seg_sum + G;

  int n4 = (4 * G) / 4;
  hipLaunchKernelGGL(zero_ws_kernel, dim3(784), dim3(256), 0, stream,
                     (float4*)d_ws, n4);

  int nseg = (M + MPB - 1) / MPB;                          // 4688
  int nmlp = (G + ROWS_PER_BLOCK - 1) / ROWS_PER_BLOCK;    // 4167
  int ntot = nseg + nmlp;
  hipLaunchKernelGGL(fused_kernel, dim3(ntot), dim3(TPB), 0, stream,
                     lm, pos, idx, gf, w, b, noise, temp,
                     seg_sum, center_raw, out, M, G, nseg, ntot);

  int nblk = (3 * G + 255) / 256;
  hipLaunchKernelGGL(norm_kernel, dim3(nblk), dim3(256), 0, stream,
                     seg_sum, center_raw, out, G);
}

// Round 12
// 95.809 us; speedup vs baseline: 1.1876x; 1.0600x over previous
//
#include <hip/hip_runtime.h>
#include <math.h>

static constexpr int CHUNK = 8;           // members per thread (seg path)
static constexpr int TPB   = 256;         // threads per block
static constexpr int MPB   = TPB * CHUNK; // 2048 members per seg block
static constexpr int LOCAL_BINS = 640;    // LDS bins cap (span/block ~43 typical)
static constexpr int ROWS_PER_BLOCK = 32; // mlp: 4 waves x 8 rows (2 quads/wave)

// ---------------------------------------------------------------------------
// Workspace zero (rocclr fillBufferAligned is slow for small fills).
// ---------------------------------------------------------------------------
__global__ __launch_bounds__(256)
void zero_ws_kernel(float4* __restrict__ ws, int n4) {
  int i = blockIdx.x * blockDim.x + threadIdx.x;
  int stride = gridDim.x * blockDim.x;
  for (; i < n4; i += stride) ws[i] = make_float4(0.f, 0.f, 0.f, 0.f);
}

// ---------------------------------------------------------------------------
// Fused kernel: R8 structure + wave-level chain merge in the seg role.
//
// seg role: 2048 members/block, LDS bins, 2 barriers. Each thread scans its
//   8-member chunk, flushing only runs CLOSED inside the chunk; the final
//   (possibly shared) run is HELD. A segmented suffix-reduce across the wave
//   (sorted order => same-segment partials are lane-contiguous) merges held
//   partials; only chain heads flush. This removes the ~6-way same-address
//   ds_atomic serialization (runlen 48 ~ 6 chunks share each bin), which
//   SQ_LDS_BANK_CONFLICT=0 cannot see. ~74 -> ~21 flushes/wave.
// mlp role: exact R8 (2 quads/wave, 8 outstanding float4 loads/lane).
// ---------------------------------------------------------------------------
__global__ __launch_bounds__(TPB)
void fused_kernel(const float* __restrict__ lm,
                  const float* __restrict__ pos,
                  const int*   __restrict__ idx,
                  const float* __restrict__ gf,
                  const float* __restrict__ w,
                  const float* __restrict__ bptr,
                  const float* __restrict__ noise,
                  const int*   __restrict__ temp_ptr,
                  float* __restrict__ seg_sum,     // [G]
                  float* __restrict__ center_raw,  // [3G]
                  float* __restrict__ out,         // [5G]
                  int M, int G, int nseg, int ntot) {
  __shared__ float bins[LOCAL_BINS * 4];

  long long r = blockIdx.x;
  int segcum  = (int)((r * (long long)nseg) / ntot);
  int segcum1 = (int)(((r + 1) * (long long)nseg) / ntot);

  if (segcum1 != segcum) {
    // ---------------- seg role ----------------
    int blockBase = segcum * MPB;
    if (blockBase >= M) return;
    int blockEnd = min(blockBase + MPB, M);
    int g_first = idx[blockBase];
    int g_last  = idx[blockEnd - 1];
    int span    = g_last - g_first + 1;
    int nbins   = min(span, LOCAL_BINS);

    for (int i = threadIdx.x; i < nbins * 4; i += TPB) bins[i] = 0.f;
    __syncthreads();

    auto flush = [&](int g, float se, float sx, float sy, float sz) {
      int off = g - g_first;
      if (off < LOCAL_BINS) {
        unsafeAtomicAdd(&bins[off*4+0], se);
        unsafeAtomicAdd(&bins[off*4+1], sx);
        unsafeAtomicAdd(&bins[off*4+2], sy);
        unsafeAtomicAdd(&bins[off*4+3], sz);
      } else {               // span-overflow fallback (statistically ~never)
        unsafeAtomicAdd(&seg_sum[g], se);
        unsafeAtomicAdd(&center_raw[3*g+0], sx);
        unsafeAtomicAdd(&center_raw[3*g+1], sy);
        unsafeAtomicAdd(&center_raw[3*g+2], sz);
      }
    };

    // ---- per-thread scan: hold the final run, flush interior runs ----
    int   heldG = -1;
    float hse = 0.f, hsx = 0.f, hsy = 0.f, hsz = 0.f;
    int   open = 0;          // 1 = entire chunk is one segment (absorbable)

    int base = blockBase + threadIdx.x * CHUNK;
    if (base < M) {
      if (base + CHUNK <= M) {
        const int4*   i4 = (const int4*)(idx + base);
        const float4* l4 = (const float4*)(lm + base);
        const float4* p4 = (const float4*)(pos + (size_t)base * 3);
        int4 ia = i4[0], ic = i4[1];
        float4 la = l4[0], lc = l4[1];
        float4 pA = p4[0], pB = p4[1], pC = p4[2],
               pD = p4[3], pE = p4[4], pF = p4[5];
        int   ib[CHUNK] = {ia.x,ia.y,ia.z,ia.w, ic.x,ic.y,ic.z,ic.w};
        float eb[CHUNK];
        eb[0]=__expf(la.x); eb[1]=__expf(la.y); eb[2]=__expf(la.z); eb[3]=__expf(la.w);
        eb[4]=__expf(lc.x); eb[5]=__expf(lc.y); eb[6]=__expf(lc.z); eb[7]=__expf(lc.w);
        float pb[CHUNK*3] = {pA.x,pA.y,pA.z,pA.w, pB.x,pB.y,pB.z,pB.w,
                             pC.x,pC.y,pC.z,pC.w, pD.x,pD.y,pD.z,pD.w,
                             pE.x,pE.y,pE.z,pE.w, pF.x,pF.y,pF.z,pF.w};

        if (ib[0] == ib[CHUNK-1]) {
          // fast path (~85%): whole chunk one segment -> hold, no flush
          open = 1; heldG = ib[0];
          #pragma unroll
          for (int j = 0; j < CHUNK; j++) {
            hse += eb[j];
            hsx += pb[3*j+0] * eb[j];
            hsy += pb[3*j+1] * eb[j];
            hsz += pb[3*j+2] * eb[j];
          }
        } else {
          int cur = ib[0];
          float se = 0.f, sx = 0.f, sy = 0.f, sz = 0.f;
          #pragma unroll
          for (int j = 0; j < CHUNK; j++) {
            if (ib[j] != cur) {
              flush(cur, se, sx, sy, sz);
              cur = ib[j]; se = 0.f; sx = 0.f; sy = 0.f; sz = 0.f;
            }
            se += eb[j];
            sx += pb[3*j+0] * eb[j];
            sy += pb[3*j+1] * eb[j];
            sz += pb[3*j+2] * eb[j];
          }
          heldG = cur; hse = se; hsx = sx; hsy = sy; hsz = sz;
        }
      } else {
        // ragged tail chunk (last block only): scalar scan, hold final run
        int nj = M - base;
        int cur = idx[base];
        float se = 0.f, sx = 0.f, sy = 0.f, sz = 0.f;
        for (int j = 0; j < nj; j++) {
          int m = base + j;
          int g = idx[m];
          float e = __expf(lm[m]);
          if (g != cur) {
            flush(cur, se, sx, sy, sz);
            cur = g; se = 0.f; sx = 0.f; sy = 0.f; sz = 0.f;
          }
          se += e;
          sx += pos[(size_t)m*3+0] * e;
          sy += pos[(size_t)m*3+1] * e;
          sz += pos[(size_t)m*3+2] * e;
        }
        heldG = cur; hse = se; hsx = sx; hsy = sy; hsz = sz;
      }
    }

    // ---- wave-level segmented suffix-reduce of held partials ----
    // lane order == member order (base = blockBase + tid*CHUNK).
    // t+1's held is absorbable into t's iff open(t+1) && key(t+1)==key(t).
    int lane = threadIdx.x & 63;
    int kR = __shfl_down(heldG, 1, 64);
    int oR = __shfl_down(open, 1, 64);
    int brk = (lane == 63) || !(oR && kR == heldG);
    #pragma unroll
    for (int s = 1; s < 64; s <<= 1) {
      float ase = __shfl_down(hse, s, 64);
      float asx = __shfl_down(hsx, s, 64);
      float asy = __shfl_down(hsy, s, 64);
      float asz = __shfl_down(hsz, s, 64);
      int  abrk = __shfl_down(brk, s, 64);
      if (!brk) { hse += ase; hsx += asx; hsy += asy; hsz += asz; }
      brk |= abrk;
    }
    int kU = __shfl_up(heldG, 1, 64);
    int head = (lane == 0) || !(open && kU == heldG);
    if (head && heldG >= 0) flush(heldG, hse, hsx, hsy, hsz);

    __syncthreads();

    for (int i = threadIdx.x; i < nbins; i += TPB) {
      int g = g_first + i;
      float s0 = bins[i*4+0], s1 = bins[i*4+1], s2 = bins[i*4+2], s3 = bins[i*4+3];
      if (g == g_first || g == g_last) {
        unsafeAtomicAdd(&seg_sum[g], s0);
        unsafeAtomicAdd(&center_raw[3*g+0], s1);
        unsafeAtomicAdd(&center_raw[3*g+1], s2);
        unsafeAtomicAdd(&center_raw[3*g+2], s3);
      } else {
        seg_sum[g] = s0;
        center_raw[3*g+0] = s1;
        center_raw[3*g+1] = s2;
        center_raw[3*g+2] = s3;
      }
    }
  } else {
    // ---------------- mlp role: 2 quads per wave (exact R8) ----------------
    int mb   = (int)(r - segcum);
    int wid  = threadIdx.x >> 6;
    int lane = threadIdx.x & 63;
    int sub  = lane & 15;
    int rg   = lane >> 4;

    int row0 = (mb * 4 + wid) * 8;
    int rowA = row0 + rg;
    int rowB = row0 + 4 + rg;

    const float4* w4 = (const float4*)w;
    float4 wv0 = w4[sub +  0], wv1 = w4[sub + 16],
           wv2 = w4[sub + 32], wv3 = w4[sub + 48];

    float dA = 0.f, dB = 0.f;
    if (rowA < G) {
      const float4* ga = (const float4*)(gf + (size_t)rowA * 256);
      const float4* gb = (const float4*)(gf + (size_t)rowB * 256);
      float4 a0 = ga[sub +  0], a1 = ga[sub + 16],
             a2 = ga[sub + 32], a3 = ga[sub + 48];
      float4 b0 = gb[sub +  0], b1 = gb[sub + 16],
             b2 = gb[sub + 32], b3 = gb[sub + 48];
      dA  = a0.x*wv0.x + a0.y*wv0.y + a0.z*wv0.z + a0.w*wv0.w;
      dA += a1.x*wv1.x + a1.y*wv1.y + a1.z*wv1.z + a1.w*wv1.w;
      dA += a2.x*wv2.x + a2.y*wv2.y + a2.z*wv2.z + a2.w*wv2.w;
      dA += a3.x*wv3.x + a3.y*wv3.y + a3.z*wv3.z + a3.w*wv3.w;
      dB  = b0.x*wv0.x + b0.y*wv0.y + b0.z*wv0.z + b0.w*wv0.w;
      dB += b1.x*wv1.x + b1.y*wv1.y + b1.z*wv1.z + b1.w*wv1.w;
      dB += b2.x*wv2.x + b2.y*wv2.y + b2.z*wv2.z + b2.w*wv2.w;
      dB += b3.x*wv3.x + b3.y*wv3.y + b3.z*wv3.z + b3.w*wv3.w;
    }
    #pragma unroll
    for (int m = 8; m >= 1; m >>= 1) {
      dA += __shfl_xor(dA, m, 64);
      dB += __shfl_xor(dB, m, 64);
    }

    if (sub == 0 && rowA < G) {
      float bb = bptr[0];
      int iv = temp_ptr[0];
      float tT = (iv > -(1 << 23) && iv < (1 << 23)) ? (float)iv : __int_as_float(iv);

      float logitA = 8.8f * tanhf(dA + bb);
      float nA = noise[rowA];
      float xA = (logitA + (logf(nA) - log1pf(-nA))) / tT;
      out[rowA]     = fminf(xA, 0.f) - log1pf(expf(-fabsf(xA)));
      out[G + rowA] = logitA;

      if (rowB < G) {
        float logitB = 8.8f * tanhf(dB + bb);
        float nB = noise[rowB];
        float xB = (logitB + (logf(nB) - log1pf(-nB))) / tT;
        out[rowB]     = fminf(xB, 0.f) - log1pf(expf(-fabsf(xB)));
        out[G + rowB] = logitB;
      }
    }
  }
}

// ---------------------------------------------------------------------------
// Center normalize: out[2G + i] = center_raw[i] / seg_sum[i/3] (0 if empty).
// ---------------------------------------------------------------------------
__global__ __launch_bounds__(256)
void norm_kernel(const float* __restrict__ seg_sum,
                 const float* __restrict__ center_raw,
                 float* __restrict__ out, int G) {
  int i = blockIdx.x * blockDim.x + threadIdx.x;
  int n = 3 * G;
  if (i < n) {
    int g = i / 3;
    float s = seg_sum[g];
    float inv = (s > 0.f) ? (1.f / s) : 0.f;
    out[(size_t)2 * G + i] = center_raw[i] * inv;
  }
}

extern "C" void kernel_launch(void* const* d_in, const int* in_sizes, int n_in,
                              void* d_out, int out_size, void* d_ws, size_t ws_size,
                              hipStream_t stream) {
  const float* gf    = (const float*)d_in[0];
  const float* pos   = (const float*)d_in[1];
  const float* lm    = (const float*)d_in[2];
  const int*   idx   = (const int*)  d_in[3];
  const float* w     = (const float*)d_in[4];
  const float* b     = (const float*)d_in[5];
  const float* noise = (const float*)d_in[6];
  const int*   temp  = (const int*)  d_in[7];
  float* out = (float*)d_out;

  int G = in_sizes[6];
  int M = in_sizes[3];

  float* seg_sum    = (float*)d_ws;
  float* center_raw = seg_sum + G;

  int n4 = (4 * G) / 4;
  hipLaunchKernelGGL(zero_ws_kernel, dim3(784), dim3(256), 0, stream,
                     (float4*)d_ws, n4);

  int nseg = (M + MPB - 1) / MPB;                          // 4688
  int nmlp = (G + ROWS_PER_BLOCK - 1) / ROWS_PER_BLOCK;    // 6250
  int ntot = nseg + nmlp;
  hipLaunchKernelGGL(fused_kernel, dim3(ntot), dim3(TPB), 0, stream,
                     lm, pos, idx, gf, w, b, noise, temp,
                     seg_sum, center_raw, out, M, G, nseg, ntot);

  int nblk = (3 * G + 255) / 256;
  hipLaunchKernelGGL(norm_kernel, dim3(nblk), dim3(256), 0, stream,
                     seg_sum, center_raw, out, G);
}